// Round 16
// baseline (308.125 us; speedup 1.0000x reference)
//
#include <hip/hip_runtime.h>
#include <cstdint>

typedef __attribute__((ext_vector_type(8))) short short8;
typedef __attribute__((ext_vector_type(4))) float f32x4;
typedef const __attribute__((address_space(1))) uint32_t gu32;
typedef __attribute__((address_space(3))) uint32_t lu32;

#define NB    18        // LDS chunk buffers
#define CHB   8192      // chunk bytes: 16 rows x 512 B (4 k-steps)
#define NSLOT 256       // 16 tiles x 16 chunks per block(CU)

__device__ __forceinline__ unsigned short bf16_rne(float f) {
    unsigned u = __float_as_uint(f);
    u += 0x7FFFu + ((u >> 16) & 1u);
    return (unsigned short)(u >> 16);
}

// W fragment table for mfma_f32_16x16x32_bf16 B-operand (R15-verified):
// ushort idx = ks*2048 + nh*1024 + hl*512 + lane*8 + b;  Wt[e][k], e=jp*32+m
__global__ __launch_bounds__(1024) void wtab_kernel(const float* __restrict__ W,
                                                    unsigned short* __restrict__ tab) {
    int el = blockIdx.x * 1024 + threadIdx.x;
    int b    = el & 7;
    int lane = (el >> 3) & 63;
    int nh   = (el >> 9) & 1;
    int ks   = el >> 10;
    int e = ks * 32 + (lane >> 4) * 8 + b;
    int k = nh * 16 + (lane & 15);
    int jp = e >> 5, m = e & 31;
    float w = W[jp * 1024 + k * 32 + m];
    unsigned short hi = bf16_rne(w);
    float fh = __uint_as_float((unsigned)hi << 16);
    unsigned short lo = bf16_rne(w - fh);
    tab[(((ks * 2 + nh) * 2 + 0) * 64 + lane) * 8 + b] = hi;
    tab[(((ks * 2 + nh) * 2 + 1) * 64 + lane) * 8 + b] = lo;
}

template <int CTRL>
__device__ __forceinline__ float dpp_add(float v) {
    int moved = __builtin_amdgcn_update_dpp(0, __float_as_int(v), CTRL, 0xF, 0xF, true);
    return v + __int_as_float(moved);
}

__device__ __forceinline__ void split8(const float4& a, const float4& b,
                                       short8& hi, short8& lo) {
    float f[8] = {a.x, a.y, a.z, a.w, b.x, b.y, b.z, b.w};
    #pragma unroll
    for (int u = 0; u < 8; ++u) {
        unsigned short h = bf16_rne(f[u]);
        hi[u] = (short)h;
        float fh = __uint_as_float((unsigned)h << 16);
        lo[u] = (short)bf16_rne(f[u] - fh);
    }
}

// 256 threads = 4 waves: kh = w&1 (k-half / C fragment), eh = w>>1 (ks-pair in chunk).
// x read ONCE: DMA-staged 8KB chunks (XOR-preswizzled source, linear LDS dest),
// ph1 = 3-pass split-bf16 MFMA from LDS; ph2 (lagged 16 slots) also from LDS.
// 18 buffers; stage(n+2) reuses exactly the buffer ph2(n-16) released (bar2-ordered).
__global__ __launch_bounds__(256, 1) void ipf_kernel(const float* __restrict__ x,
                                                     const unsigned short* __restrict__ tab,
                                                     float* __restrict__ out) {
    extern __shared__ char smem[];
    char* xbuf = smem;                            // NB * 8192
    float* Sp = (float*)(smem + NB * CHB);        // [4][16][17] partial S
    float* Sl = Sp + 4 * 16 * 17;                 // [2][16][36] final S, dbuf
    const int t = threadIdx.x;
    const int w = t >> 6, l = t & 63;
    const int kh = w & 1, eh = w >> 1;
    const long long base = (long long)blockIdx.x * 256;    // batches
    const char* gx = (const char*)(x + base * 2048);

    f32x4 c = {0.f, 0.f, 0.f, 0.f};

    // stage chunk n: 2 DMA instrs/wave; source pre-swizzled so LDS[row][cb] = x[row][cb ^ key(row)]
    auto STAGE = [&](int n) {
        const int bn = n % NB;
        const size_t tb = (size_t)(n >> 4) * 131072 + (size_t)(n & 15) * 512;
        #pragma unroll
        for (int u = 0; u < 2; ++u) {
            const int row = w * 4 + u * 2 + (l >> 5);
            const char* gs = gx + tb + (size_t)row * 8192
                           + (((l & 31) * 16) ^ ((row & 7) * 16));
            __builtin_amdgcn_global_load_lds((gu32*)gs,
                (lu32*)(xbuf + bn * CHB + w * 2048 + u * 1024), 16, 0, 0);
        }
    };

    // ph2 of chunk m: 64 dots (16b x 4 channels), 4 lanes/dot
    auto PH2 = [&](int m) {
        const int bm = m % NB, cm = m & 15, tp = m >> 4, sb = tp & 1;
        const int did = l >> 2, sub = l & 3;
        const int b = w * 4 + (did >> 2), il = did & 3;
        const int key = (b & 7) * 16;
        const char* rp = xbuf + bm * CHB + b * 512;
        const int fb = il * 128 + sub * 32;
        const float4 x0 = *(const float4*)(rp + (fb ^ key));
        const float4 x1 = *(const float4*)(rp + ((fb + 16) ^ key));
        const float* sp = Sl + sb * 576 + b * 36 + sub * 8;
        const float4 s0 = *(const float4*)sp;
        const float4 s1 = *(const float4*)(sp + 4);
        float s = x0.x * s0.x + x0.y * s0.y + x0.z * s0.z + x0.w * s0.w
                + x1.x * s1.x + x1.y * s1.y + x1.z * s1.z + x1.w * s1.w;
        s = dpp_add<0x111>(s);
        s = dpp_add<0x112>(s);                    // lane sub==3 holds the 32-d dot
        if (sub == 3) {
            const float e2 = __expf(2.0f * s);    // tanh = 1 - 2/(e^{2s}+1)
            out[(base + tp * 16 + b) * 64 + cm * 4 + il] = 1.0f - 2.0f / (e2 + 1.0f);
        }
    };

    // tile boundary: C -> Sp, reduce eh-pairs -> S[tile&1], re-zero C
    auto FOLD = [&](int tile) {
        #pragma unroll
        for (int rr = 0; rr < 4; ++rr)            // C: row=(l>>4)*4+rr, col=l&15 (m89)
            Sp[w * 272 + ((l >> 4) * 4 + rr) * 17 + (l & 15)] = c[rr];
        c[0] = 0.f; c[1] = 0.f; c[2] = 0.f; c[3] = 0.f;
        asm volatile("s_waitcnt lgkmcnt(0)" ::: "memory");
        __builtin_amdgcn_s_barrier();
        const int sb = tile & 1;
        #pragma unroll
        for (int u = 0; u < 2; ++u) {
            const int sidx = t + u * 256;         // 512 items = 16b x 32k
            const int b_ = sidx >> 5, k_ = sidx & 31;
            const int kh_ = k_ >> 4, kk_ = k_ & 15;
            Sl[sb * 576 + b_ * 36 + k_] =
                Sp[kh_ * 272 + b_ * 17 + kk_] + Sp[(kh_ + 2) * 272 + b_ * 17 + kk_];
        }
        asm volatile("s_waitcnt lgkmcnt(0)" ::: "memory");
        __builtin_amdgcn_s_barrier();
    };

    STAGE(0);
    STAGE(1);

    #pragma unroll 1
    for (int n = 0; n < NSLOT; ++n) {
        if ((n & 15) == 0 && n > 0) FOLD((n >> 4) - 1);
        // stage(n+1)'s 2 instrs are always the newest -> vmcnt(2) retires stage(n)+older
        if (n < NSLOT - 1) asm volatile("s_waitcnt vmcnt(2)" ::: "memory");
        else               asm volatile("s_waitcnt vmcnt(0)" ::: "memory");
        __builtin_amdgcn_s_barrier();             // bar1: all waves' chunk-n pieces landed
        __builtin_amdgcn_sched_barrier(0);

        // ---- ph1: 2 ks, 3-pass split-bf16 MFMA ----
        {
            const int bn = n % NB;
            const int r = l & 15, h = l >> 4;
            const int key = (r & 7) * 16;
            const char* rp = xbuf + bn * CHB + r * 512;
            #pragma unroll
            for (int q2 = 0; q2 < 2; ++q2) {
                const int ksl = 2 * eh + q2;
                const int ksg = (n & 15) * 4 + ksl;
                const int fb = ksl * 128 + h * 32;
                const float4 xa  = *(const float4*)(rp + (fb ^ key));
                const float4 xb2 = *(const float4*)(rp + ((fb + 16) ^ key));
                const short8* tpp = (const short8*)(tab + (size_t)ksg * 2048 + kh * 1024) + l;
                const short8 wh = tpp[0];
                const short8 wl = tpp[64];
                short8 xhi, xlo;
                split8(xa, xb2, xhi, xlo);
                c = __builtin_amdgcn_mfma_f32_16x16x32_bf16(xhi, wh, c, 0, 0, 0);
                c = __builtin_amdgcn_mfma_f32_16x16x32_bf16(xhi, wl, c, 0, 0, 0);
                c = __builtin_amdgcn_mfma_f32_16x16x32_bf16(xlo, wh, c, 0, 0, 0);
            }
        }

        if (n >= 16) PH2(n - 16);                 // frees buffer (n-16)%NB == (n+2)%NB

        asm volatile("s_waitcnt lgkmcnt(0)" ::: "memory");
        __builtin_amdgcn_s_barrier();             // bar2: all ph2 reads done before overwrite
        __builtin_amdgcn_sched_barrier(0);
        if (n + 2 < NSLOT) STAGE(n + 2);
    }

    FOLD(15);
    #pragma unroll 1
    for (int m = NSLOT - 16; m < NSLOT; ++m) PH2(m);   // epilogue: tile 15's phase-2
}

extern "C" void kernel_launch(void* const* d_in, const int* in_sizes, int n_in,
                              void* d_out, int out_size, void* d_ws, size_t ws_size,
                              hipStream_t stream) {
    const float* x = (const float*)d_in[0];          // [65536,64,32] fp32
    const float* W = (const float*)d_in[1];          // [64,32,32] fp32
    float* out = (float*)d_out;                      // [65536,64] fp32
    unsigned short* tab = (unsigned short*)d_ws;     // 131072 ushorts = 256 KB

    const size_t smem_bytes = (size_t)NB * CHB + (4 * 16 * 17 + 2 * 16 * 36) * sizeof(float); // 156416
    hipFuncSetAttribute((const void*)ipf_kernel,
                        hipFuncAttributeMaxDynamicSharedMemorySize, (int)smem_bytes);

    wtab_kernel<<<64, 1024, 0, stream>>>(W, tab);
    ipf_kernel<<<256, 256, smem_bytes, stream>>>(x, tab, out);
}

// Round 17
// 293.484 us; speedup vs baseline: 1.0499x; 1.0499x over previous
//
#include <hip/hip_runtime.h>
#include <cstdint>

typedef __attribute__((ext_vector_type(8))) short short8;
typedef __attribute__((ext_vector_type(4))) float f32x4;
typedef const __attribute__((address_space(1))) uint32_t gu32;
typedef __attribute__((address_space(3))) uint32_t lu32;

#define NB    18        // LDS chunk buffers
#define CHB   8192      // chunk bytes: 16 rows x 512 B (4 k-steps)
#define NSLOT 256       // 16 tiles x 16 chunks per block(CU)

__device__ __forceinline__ unsigned short bf16_rne(float f) {
    unsigned u = __float_as_uint(f);
    u += 0x7FFFu + ((u >> 16) & 1u);
    return (unsigned short)(u >> 16);
}

// W fragment table for mfma_f32_16x16x32_bf16 B-operand (R15/R16-verified):
// ushort idx = ks*2048 + nh*1024 + hl*512 + lane*8 + b;  Wt[e][k], e=jp*32+m
__global__ __launch_bounds__(1024) void wtab_kernel(const float* __restrict__ W,
                                                    unsigned short* __restrict__ tab) {
    int el = blockIdx.x * 1024 + threadIdx.x;
    int b    = el & 7;
    int lane = (el >> 3) & 63;
    int nh   = (el >> 9) & 1;
    int ks   = el >> 10;
    int e = ks * 32 + (lane >> 4) * 8 + b;
    int k = nh * 16 + (lane & 15);
    int jp = e >> 5, m = e & 31;
    float w = W[jp * 1024 + k * 32 + m];
    unsigned short hi = bf16_rne(w);
    float fh = __uint_as_float((unsigned)hi << 16);
    unsigned short lo = bf16_rne(w - fh);
    tab[(((ks * 2 + nh) * 2 + 0) * 64 + lane) * 8 + b] = hi;
    tab[(((ks * 2 + nh) * 2 + 1) * 64 + lane) * 8 + b] = lo;
}

template <int CTRL>
__device__ __forceinline__ float dpp_add(float v) {
    int moved = __builtin_amdgcn_update_dpp(0, __float_as_int(v), CTRL, 0xF, 0xF, true);
    return v + __int_as_float(moved);
}

__device__ __forceinline__ void split8(const float4& a, const float4& b,
                                       short8& hi, short8& lo) {
    float f[8] = {a.x, a.y, a.z, a.w, b.x, b.y, b.z, b.w};
    #pragma unroll
    for (int u = 0; u < 8; ++u) {
        unsigned short h = bf16_rne(f[u]);
        hi[u] = (short)h;
        float fh = __uint_as_float((unsigned)h << 16);
        lo[u] = (short)bf16_rne(f[u] - fh);
    }
}

// 512 threads = 8 waves = kh(2, N-half) x kso(4, ks within chunk); 2 waves/SIMD.
// x read ONCE via 8KB DMA chunks (XOR-preswizzled source, linear LDS dest);
// ph1 = 3-pass split-bf16 MFMA; ph2 lagged 16 slots from LDS; single Sl buffer.
__global__ __launch_bounds__(512, 1) void ipf_kernel(const float* __restrict__ x,
                                                     const unsigned short* __restrict__ tab,
                                                     float* __restrict__ out) {
    extern __shared__ char smem[];
    char* xbuf = smem;                            // NB * 8192
    float* Sp = (float*)(smem + NB * CHB);        // [4][16][34] partial S (kso-fragments)
    float* Sl = Sp + 4 * 16 * 34;                 // [16][36] final S
    const int t = threadIdx.x;
    const int w = t >> 6, l = t & 63;
    const int kh = w & 1, kso = w >> 1;
    const long long base = (long long)blockIdx.x * 256;    // batches
    const char* gx = (const char*)(x + base * 2048);

    f32x4 c = {0.f, 0.f, 0.f, 0.f};

    // stage chunk n (tile n>>4, cols [(n&15)*128, +128)): wave stages 2 rows = 1KB = 1 DMA
    auto STAGE = [&](int n, int bnn) {
        const int tt = n >> 4, cc = n & 15;
        const int r = w * 2 + (l >> 5);
        const char* gs = gx + ((size_t)(tt * 16 + r) << 13) + cc * 512
                       + (((l & 31) * 16) ^ ((r & 7) * 16));
        __builtin_amdgcn_global_load_lds((gu32*)gs,
            (lu32*)(xbuf + bnn * CHB + w * 1024), 16, 0, 0);
    };

    // ph2 of chunk m: 64 dots (16 batches x 4 channels), 8 lanes/dot
    auto PH2 = [&](int m, int bm) {
        const int b = 2 * w + (l >> 5);
        const int il = (l >> 3) & 3;
        const int h = l & 7;
        const char* rp = xbuf + bm * CHB + b * 512;
        const float4 xv = *(const float4*)(rp + ((il * 128 + h * 16) ^ ((b & 7) * 16)));
        const float4 sv = *(const float4*)(Sl + b * 36 + h * 4);
        float s = xv.x * sv.x + xv.y * sv.y + xv.z * sv.z + xv.w * sv.w;
        s = dpp_add<0x111>(s);
        s = dpp_add<0x112>(s);
        s = dpp_add<0x114>(s);                    // lane h==7 holds the 32-d dot
        if (h == 7) {
            const float e2 = __expf(2.0f * s);    // tanh = 1 - 2/(e^{2s}+1)
            out[(base + (m >> 4) * 16 + b) * 64 + (m & 15) * 4 + il] = 1.0f - 2.0f / (e2 + 1.0f);
        }
    };

    // tile boundary: dump C fragments -> Sp, reduce kso -> Sl, re-zero C
    auto FOLD = [&]() {
        #pragma unroll
        for (int rr = 0; rr < 4; ++rr)            // C (m89): row=(l>>4)*4+rr, col=l&15
            Sp[kso * 544 + ((l >> 4) * 4 + rr) * 34 + kh * 17 + (l & 15)] = c[rr];
        c[0] = 0.f; c[1] = 0.f; c[2] = 0.f; c[3] = 0.f;
        asm volatile("s_waitcnt lgkmcnt(0)" ::: "memory");
        __builtin_amdgcn_s_barrier();
        {
            const int b = t >> 5, k = t & 31;     // 512 threads = 16b x 32k
            const int kh_ = k >> 4, kk = k & 15;
            float v = 0.f;
            #pragma unroll
            for (int q = 0; q < 4; ++q)
                v += Sp[q * 544 + b * 34 + kh_ * 17 + kk];
            Sl[b * 36 + k] = v;
        }
        asm volatile("s_waitcnt lgkmcnt(0)" ::: "memory");
        __builtin_amdgcn_s_barrier();
    };

    STAGE(0, 0);
    STAGE(1, 1);

    int bn = 0;                                   // n % NB via running counter
    #pragma unroll 1
    for (int n = 0; n < NSLOT; ++n) {
        if ((n & 15) == 0 && n > 0) FOLD();
        // per-wave VMEM instrs: stage=1, ph2-store=1. Steady queue at slot top:
        // [store(n-2), stage(n), store(n-1), stage(n+1)] -> vmcnt(2) retires stage(n).
        // n<17 (no stores yet) / n==NSLOT-1 (no stage(n+1) pending pattern): vmcnt(1).
        if (n >= 17 && n < NSLOT - 1) asm volatile("s_waitcnt vmcnt(2)" ::: "memory");
        else                          asm volatile("s_waitcnt vmcnt(1)" ::: "memory");
        __builtin_amdgcn_s_barrier();             // bar1: chunk n resident
        __builtin_amdgcn_sched_barrier(0);

        // ---- ph1: 1 ks, 3-pass split-bf16 MFMA ----
        {
            const int r = l & 15;
            const int hq = l >> 4;
            const int ksg = (n & 15) * 4 + kso;
            const int cb = kso * 128 + hq * 32;
            const int key = (r & 7) * 16;
            const char* rp = xbuf + bn * CHB + r * 512;
            const float4 xa  = *(const float4*)(rp + (cb ^ key));
            const float4 xb2 = *(const float4*)(rp + ((cb + 16) ^ key));
            const short8* tpp = (const short8*)(tab + (size_t)ksg * 2048 + kh * 1024) + l;
            const short8 wh = tpp[0];
            const short8 wl = tpp[64];
            short8 xhi, xlo;
            split8(xa, xb2, xhi, xlo);
            c = __builtin_amdgcn_mfma_f32_16x16x32_bf16(xhi, wh, c, 0, 0, 0);
            c = __builtin_amdgcn_mfma_f32_16x16x32_bf16(xhi, wl, c, 0, 0, 0);
            c = __builtin_amdgcn_mfma_f32_16x16x32_bf16(xlo, wh, c, 0, 0, 0);
        }

        int bm = bn + 2; if (bm >= NB) bm -= NB;  // (n+2)%NB == (n-16)%NB
        if (n >= 16) PH2(n - 16, bm);

        asm volatile("s_waitcnt lgkmcnt(0)" ::: "memory");
        __builtin_amdgcn_s_barrier();             // bar2: ph2 reads done before DMA overwrite
        __builtin_amdgcn_sched_barrier(0);
        if (n + 2 < NSLOT) STAGE(n + 2, bm);

        bn = (bn + 1 == NB) ? 0 : bn + 1;
    }

    FOLD();                                       // tile 15
    #pragma unroll 1
    for (int m = NSLOT - 16; m < NSLOT; ++m)      // epilogue ph2 (chunks all resident)
        PH2(m, m % NB);
}

extern "C" void kernel_launch(void* const* d_in, const int* in_sizes, int n_in,
                              void* d_out, int out_size, void* d_ws, size_t ws_size,
                              hipStream_t stream) {
    const float* x = (const float*)d_in[0];          // [65536,64,32] fp32
    const float* W = (const float*)d_in[1];          // [64,32,32] fp32
    float* out = (float*)d_out;                      // [65536,64] fp32
    unsigned short* tab = (unsigned short*)d_ws;     // 131072 ushorts = 256 KB

    const size_t smem_bytes = (size_t)NB * CHB + (4 * 16 * 34 + 16 * 36) * sizeof(float); // 158464
    hipFuncSetAttribute((const void*)ipf_kernel,
                        hipFuncAttributeMaxDynamicSharedMemorySize, (int)smem_bytes);

    wtab_kernel<<<64, 1024, 0, stream>>>(W, tab);
    ipf_kernel<<<256, 512, smem_bytes, stream>>>(x, tab, out);
}

// Round 18
// 284.634 us; speedup vs baseline: 1.0825x; 1.0311x over previous
//
#include <hip/hip_runtime.h>
#include <cstdint>

typedef __attribute__((ext_vector_type(8))) short short8;
typedef __attribute__((ext_vector_type(4))) float f32x4;

__device__ __forceinline__ unsigned short bf16_rne(float f) {
    unsigned u = __float_as_uint(f);
    u += 0x7FFFu + ((u >> 16) & 1u);
    return (unsigned short)(u >> 16);
}

// W fragment table for mfma_f32_16x16x32_bf16 B-operand (R15-verified):
// ushort idx = ks*2048 + nh*1024 + hl*512 + lane*8 + b;  Wt[e][k], e=jp*32+m
__global__ __launch_bounds__(1024) void wtab_kernel(const float* __restrict__ W,
                                                    unsigned short* __restrict__ tab) {
    int el = blockIdx.x * 1024 + threadIdx.x;   // 65536 elements
    int b    = el & 7;
    int lane = (el >> 3) & 63;
    int nh   = (el >> 9) & 1;
    int ks   = el >> 10;
    int e = ks * 32 + (lane >> 4) * 8 + b;
    int k = nh * 16 + (lane & 15);
    int jp = e >> 5, m = e & 31;
    float w = W[jp * 1024 + k * 32 + m];
    unsigned short hi = bf16_rne(w);
    float fh = __uint_as_float((unsigned)hi << 16);
    unsigned short lo = bf16_rne(w - fh);
    tab[(((ks * 2 + nh) * 2 + 0) * 64 + lane) * 8 + b] = hi;
    tab[(((ks * 2 + nh) * 2 + 1) * 64 + lane) * 8 + b] = lo;
}

__device__ __forceinline__ void split8(const float4& a, const float4& b,
                                       short8& hi, short8& lo) {
    float f[8] = {a.x, a.y, a.z, a.w, b.x, b.y, b.z, b.w};
    #pragma unroll
    for (int u = 0; u < 8; ++u) {
        unsigned short h = bf16_rne(f[u]);
        hi[u] = (short)h;
        float fh = __uint_as_float((unsigned)h << 16);
        lo[u] = (short)bf16_rne(f[u] - fh);
    }
}

// 256 threads = 4 independent waves; wave owns an M-tile of 16 batches. No barriers.
// k-loop software-pipelined: ping-pong register buffers xA/xB hold 4 ks (32 floats)
// of HBM A-fragments, prefetched one half-block (~900 cy) ahead of compute.
// tab (256 KB, L2-hot) loaded at use. 3-pass split-bf16 MFMA (R15-verified).
__global__ __launch_bounds__(256, 2) void ipf_kernel(const float* __restrict__ x,
                                                     const unsigned short* __restrict__ tab,
                                                     float* __restrict__ out) {
    __shared__ float Sl[4][16 * 36];
    const int t = threadIdx.x;
    const int w = t >> 6, l = t & 63;
    const long long b0 = ((long long)blockIdx.x * 4 + w) * 16;

    const float* xrow = x + (b0 + (l & 15)) * 2048 + (l >> 4) * 8;   // A-frag base
    f32x4 c0 = {0.f, 0.f, 0.f, 0.f};
    f32x4 c1 = {0.f, 0.f, 0.f, 0.f};

    float4 xA[4][2], xB[4][2];

    #define PREFETCH(XR, kb)                                                      \
        _Pragma("unroll")                                                         \
        for (int u = 0; u < 4; ++u) {                                             \
            XR[u][0] = *(const float4*)(xrow + (kb) * 128 + u * 32);              \
            XR[u][1] = *(const float4*)(xrow + (kb) * 128 + u * 32 + 4);          \
        }

    #define COMPUTE(XR, kb)                                                       \
        _Pragma("unroll")                                                         \
        for (int u = 0; u < 4; ++u) {                                             \
            const int ks = (kb) * 4 + u;                                          \
            const short8* tp = (const short8*)(tab + (size_t)ks * 2048);          \
            const short8 wh0 = tp[l];                                             \
            const short8 wl0 = tp[64 + l];                                        \
            const short8 wh1 = tp[128 + l];                                       \
            const short8 wl1 = tp[192 + l];                                       \
            short8 xhi, xlo;                                                      \
            split8(XR[u][0], XR[u][1], xhi, xlo);                                 \
            c0 = __builtin_amdgcn_mfma_f32_16x16x32_bf16(xhi, wh0, c0, 0, 0, 0);  \
            c1 = __builtin_amdgcn_mfma_f32_16x16x32_bf16(xhi, wh1, c1, 0, 0, 0);  \
            c0 = __builtin_amdgcn_mfma_f32_16x16x32_bf16(xhi, wl0, c0, 0, 0, 0);  \
            c1 = __builtin_amdgcn_mfma_f32_16x16x32_bf16(xhi, wl1, c1, 0, 0, 0);  \
            c0 = __builtin_amdgcn_mfma_f32_16x16x32_bf16(xlo, wh0, c0, 0, 0, 0);  \
            c1 = __builtin_amdgcn_mfma_f32_16x16x32_bf16(xlo, wh1, c1, 0, 0, 0);  \
        }

    PREFETCH(xA, 0);
    #pragma unroll 1
    for (int kb2 = 0; kb2 < 8; ++kb2) {
        const int kbB  = 2 * kb2 + 1;
        const int kbA2 = (kb2 < 7) ? 2 * kb2 + 2 : 15;   // clamped dummy on last iter
        PREFETCH(xB, kbB);
        COMPUTE(xA, 2 * kb2);
        PREFETCH(xA, kbA2);
        COMPUTE(xB, kbB);
    }
    #undef PREFETCH
    #undef COMPUTE

    // D layout (m89-verified): row(batch) = (l>>4)*4 + r, col(k) = l&15.
    float* S = &Sl[w][0];                    // stride 36: write conflicts <=2-way
    #pragma unroll
    for (int r = 0; r < 4; ++r) {
        S[((l >> 4) * 4 + r) * 36 + (l & 15)]      = c0[r];
        S[((l >> 4) * 4 + r) * 36 + 16 + (l & 15)] = c1[r];
    }
    asm volatile("s_waitcnt lgkmcnt(0)" ::: "memory");   // wave-local LDS, no barrier

    // phase 2: out[b0+r, i=l] = tanh(sum_d x[b0+r][l*32+d] * S[r][d]); x re-read L2-hot
    const float* xb2 = x + b0 * 2048;
    #pragma unroll 2
    for (int r = 0; r < 16; ++r) {
        const float* xr = xb2 + r * 2048 + l * 32;     // 64 lanes x 128B contiguous
        const float* sr = S + r * 36;                  // broadcast reads
        float s = 0.0f;
        #pragma unroll
        for (int q = 0; q < 8; ++q) {
            const float4 xv = *(const float4*)(xr + q * 4);
            s += xv.x * sr[q * 4] + xv.y * sr[q * 4 + 1]
               + xv.z * sr[q * 4 + 2] + xv.w * sr[q * 4 + 3];
        }
        const float e2 = __expf(2.0f * s);             // tanh = 1 - 2/(e^{2s}+1)
        out[(b0 + r) * 64 + l] = 1.0f - 2.0f / (e2 + 1.0f);
    }
}

extern "C" void kernel_launch(void* const* d_in, const int* in_sizes, int n_in,
                              void* d_out, int out_size, void* d_ws, size_t ws_size,
                              hipStream_t stream) {
    const float* x = (const float*)d_in[0];          // [65536,64,32] fp32
    const float* W = (const float*)d_in[1];          // [64,32,32] fp32
    float* out = (float*)d_out;                      // [65536,64] fp32
    unsigned short* tab = (unsigned short*)d_ws;     // 131072 ushorts = 256 KB

    wtab_kernel<<<64, 1024, 0, stream>>>(W, tab);
    ipf_kernel<<<1024, 256, 0, stream>>>(x, tab, out);
}

// Round 19
// 254.248 us; speedup vs baseline: 1.2119x; 1.1195x over previous
//
#include <hip/hip_runtime.h>
#include <cstdint>

typedef __attribute__((ext_vector_type(8))) short short8;
typedef __attribute__((ext_vector_type(4))) float f32x4;

__device__ __forceinline__ unsigned short bf16_rne(float f) {
    unsigned u = __float_as_uint(f);
    u += 0x7FFFu + ((u >> 16) & 1u);
    return (unsigned short)(u >> 16);
}

// W fragment table for mfma_f32_16x16x32_bf16 B-operand (R15-verified):
// ushort idx = ks*2048 + nh*1024 + hl*512 + lane*8 + b;  Wt[e][k], e=jp*32+m
__global__ __launch_bounds__(1024) void wtab_kernel(const float* __restrict__ W,
                                                    unsigned short* __restrict__ tab) {
    int el = blockIdx.x * 1024 + threadIdx.x;   // 65536 elements
    int b    = el & 7;
    int lane = (el >> 3) & 63;
    int nh   = (el >> 9) & 1;
    int ks   = el >> 10;
    int e = ks * 32 + (lane >> 4) * 8 + b;
    int k = nh * 16 + (lane & 15);
    int jp = e >> 5, m = e & 31;
    float w = W[jp * 1024 + k * 32 + m];
    unsigned short hi = bf16_rne(w);
    float fh = __uint_as_float((unsigned)hi << 16);
    unsigned short lo = bf16_rne(w - fh);
    tab[(((ks * 2 + nh) * 2 + 0) * 64 + lane) * 8 + b] = hi;
    tab[(((ks * 2 + nh) * 2 + 1) * 64 + lane) * 8 + b] = lo;
}

__device__ __forceinline__ void split8(const float4& a, const float4& b,
                                       short8& hi, short8& lo) {
    float f[8] = {a.x, a.y, a.z, a.w, b.x, b.y, b.z, b.w};
    #pragma unroll
    for (int u = 0; u < 8; ++u) {
        unsigned short h = bf16_rne(f[u]);
        hi[u] = (short)h;
        float fh = __uint_as_float((unsigned)h << 16);
        lo[u] = (short)bf16_rne(f[u] - fh);
    }
}

// 256 threads = 4 independent waves; wave owns an M-tile of 16 batches. No barriers.
// k-loop ping-pong prefetch with sched_barrier(0) fences: each 8-load batch is
// ISSUED before the other buffer's compute (compiler cannot sink across the
// fence), waited only at first use inside the next compute (counted vmcnt,
// auto-inserted). No launch_bounds VGPR cap -> buffers stay live in registers.
__global__ __launch_bounds__(256) void ipf_kernel(const float* __restrict__ x,
                                                  const unsigned short* __restrict__ tab,
                                                  float* __restrict__ out) {
    __shared__ float Sl[4][16 * 36];
    const int t = threadIdx.x;
    const int w = t >> 6, l = t & 63;
    const long long b0 = ((long long)blockIdx.x * 4 + w) * 16;

    const float* xrow = x + (b0 + (l & 15)) * 2048 + (l >> 4) * 8;   // A-frag base
    f32x4 c0 = {0.f, 0.f, 0.f, 0.f};
    f32x4 c1 = {0.f, 0.f, 0.f, 0.f};

    float4 xA[4][2], xB[4][2];

    #define PREFETCH(XR, kb)                                                      \
        _Pragma("unroll")                                                         \
        for (int u = 0; u < 4; ++u) {                                             \
            XR[u][0] = *(const float4*)(xrow + (kb) * 128 + u * 32);              \
            XR[u][1] = *(const float4*)(xrow + (kb) * 128 + u * 32 + 4);          \
        }                                                                         \
        __builtin_amdgcn_sched_barrier(0);   /* loads may not sink below here */

    #define COMPUTE(XR, kb)                                                       \
        _Pragma("unroll")                                                         \
        for (int u = 0; u < 4; ++u) {                                             \
            const int ks = (kb) * 4 + u;                                          \
            const short8* tp = (const short8*)(tab + (size_t)ks * 2048);          \
            const short8 wh0 = tp[l];                                             \
            const short8 wl0 = tp[64 + l];                                        \
            const short8 wh1 = tp[128 + l];                                       \
            const short8 wl1 = tp[192 + l];                                       \
            short8 xhi, xlo;                                                      \
            split8(XR[u][0], XR[u][1], xhi, xlo);                                 \
            c0 = __builtin_amdgcn_mfma_f32_16x16x32_bf16(xhi, wh0, c0, 0, 0, 0);  \
            c1 = __builtin_amdgcn_mfma_f32_16x16x32_bf16(xhi, wh1, c1, 0, 0, 0);  \
            c0 = __builtin_amdgcn_mfma_f32_16x16x32_bf16(xhi, wl0, c0, 0, 0, 0);  \
            c1 = __builtin_amdgcn_mfma_f32_16x16x32_bf16(xhi, wl1, c1, 0, 0, 0);  \
            c0 = __builtin_amdgcn_mfma_f32_16x16x32_bf16(xlo, wh0, c0, 0, 0, 0);  \
            c1 = __builtin_amdgcn_mfma_f32_16x16x32_bf16(xlo, wh1, c1, 0, 0, 0);  \
        }

    PREFETCH(xA, 0);
    #pragma unroll 1
    for (int kb2 = 0; kb2 < 8; ++kb2) {
        const int kbB  = 2 * kb2 + 1;
        const int kbA2 = (kb2 < 7) ? 2 * kb2 + 2 : 15;   // clamped dummy on last iter
        PREFETCH(xB, kbB);           // issued BEFORE compute of xA (fenced)
        COMPUTE(xA, 2 * kb2);        // first use of xA -> counted vmcnt here
        PREFETCH(xA, kbA2);          // issued BEFORE compute of xB (fenced)
        COMPUTE(xB, kbB);
    }
    #undef PREFETCH
    #undef COMPUTE

    // D layout (m89-verified): row(batch) = (l>>4)*4 + r, col(k) = l&15.
    float* S = &Sl[w][0];                    // stride 36: write conflicts <=2-way
    #pragma unroll
    for (int r = 0; r < 4; ++r) {
        S[((l >> 4) * 4 + r) * 36 + (l & 15)]      = c0[r];
        S[((l >> 4) * 4 + r) * 36 + 16 + (l & 15)] = c1[r];
    }
    asm volatile("s_waitcnt lgkmcnt(0)" ::: "memory");   // wave-local LDS, no barrier

    // phase 2: out[b0+r, i=l] = tanh(sum_d x[b0+r][l*32+d] * S[r][d]); x re-read L2/L3-hot
    const float* xb2 = x + b0 * 2048;
    #pragma unroll 2
    for (int r = 0; r < 16; ++r) {
        const float* xr = xb2 + r * 2048 + l * 32;     // 64 lanes x 128B contiguous
        const float* sr = S + r * 36;                  // broadcast reads
        float s = 0.0f;
        #pragma unroll
        for (int q = 0; q < 8; ++q) {
            const float4 xv = *(const float4*)(xr + q * 4);
            s += xv.x * sr[q * 4] + xv.y * sr[q * 4 + 1]
               + xv.z * sr[q * 4 + 2] + xv.w * sr[q * 4 + 3];
        }
        const float e2 = __expf(2.0f * s);             // tanh = 1 - 2/(e^{2s}+1)
        out[(b0 + r) * 64 + l] = 1.0f - 2.0f / (e2 + 1.0f);
    }
}

extern "C" void kernel_launch(void* const* d_in, const int* in_sizes, int n_in,
                              void* d_out, int out_size, void* d_ws, size_t ws_size,
                              hipStream_t stream) {
    const float* x = (const float*)d_in[0];          // [65536,64,32] fp32
    const float* W = (const float*)d_in[1];          // [64,32,32] fp32
    float* out = (float*)d_out;                      // [65536,64] fp32
    unsigned short* tab = (unsigned short*)d_ws;     // 131072 ushorts = 256 KB

    wtab_kernel<<<64, 1024, 0, stream>>>(W, tab);
    ipf_kernel<<<1024, 256, 0, stream>>>(x, tab, out);
}

// Round 20
// 200.644 us; speedup vs baseline: 1.5357x; 1.2672x over previous
//
#include <hip/hip_runtime.h>
#include <cstdint>

typedef __attribute__((ext_vector_type(8))) short short8;
typedef __attribute__((ext_vector_type(4))) float f32x4;
typedef const __attribute__((address_space(1))) uint32_t gu32;
typedef __attribute__((address_space(3))) uint32_t lu32;

#define WLDS 18688   // per-wave LDS bytes: 16KB ring + 16*36 floats S

__device__ __forceinline__ unsigned short bf16_rne(float f) {
    unsigned u = __float_as_uint(f);
    u += 0x7FFFu + ((u >> 16) & 1u);
    return (unsigned short)(u >> 16);
}

// W fragment table for mfma_f32_16x16x32_bf16 B-operand (R15-verified):
// ushort idx = ks*2048 + nh*1024 + hl*512 + lane*8 + b;  Wt[e][k], e=jp*32+m
__global__ __launch_bounds__(1024) void wtab_kernel(const float* __restrict__ W,
                                                    unsigned short* __restrict__ tab) {
    int el = blockIdx.x * 1024 + threadIdx.x;   // 65536 elements
    int b    = el & 7;
    int lane = (el >> 3) & 63;
    int nh   = (el >> 9) & 1;
    int ks   = el >> 10;
    int e = ks * 32 + (lane >> 4) * 8 + b;
    int k = nh * 16 + (lane & 15);
    int jp = e >> 5, m = e & 31;
    float w = W[jp * 1024 + k * 32 + m];
    unsigned short hi = bf16_rne(w);
    float fh = __uint_as_float((unsigned)hi << 16);
    unsigned short lo = bf16_rne(w - fh);
    tab[(((ks * 2 + nh) * 2 + 0) * 64 + lane) * 8 + b] = hi;
    tab[(((ks * 2 + nh) * 2 + 1) * 64 + lane) * 8 + b] = lo;
}

__device__ __forceinline__ void split8(const float4& a, const float4& b,
                                       short8& hi, short8& lo) {
    float f[8] = {a.x, a.y, a.z, a.w, b.x, b.y, b.z, b.w};
    #pragma unroll
    for (int u = 0; u < 8; ++u) {
        unsigned short h = bf16_rne(f[u]);
        hi[u] = (short)h;
        float fh = __uint_as_float((unsigned)h << 16);
        lo[u] = (short)bf16_rne(f[u] - fh);
    }
}

// 256 threads = 4 fully independent waves (ZERO barriers). Wave owns 16 batches.
// All x movement via per-wave global_load_lds rings with hand-counted vmcnt:
// ph1: 4x4KB chunk ring (2 ks/chunk, XOR-swizzled A-frag layout), depth-2;
// ph2: 2x8KB row ring (lane = channel, full dot in-lane, no reduce), depth-2.
// tab loads (L2-hot) are part of the fixed per-iter VMEM rhythm and are
// counted by the waits, never drained.
__global__ __launch_bounds__(256) void ipf_kernel(const float* __restrict__ x,
                                                  const unsigned short* __restrict__ tab,
                                                  float* __restrict__ out) {
    extern __shared__ char smem[];
    const int t = threadIdx.x;
    const int w = t >> 6, l = t & 63;
    char* ring = smem + w * WLDS;                 // 16 KB ring
    float* Sl = (float*)(ring + 16384);           // 16 x 36 floats
    const long long b0 = ((long long)blockIdx.x * 4 + w) * 16;
    const char* gxt = (const char*)(x + b0 * 2048);   // 16 rows x 8 KB

    // ph1 stage chunk c (cols [c*256B, +256B) of all 16 rows): 4 DMA instrs.
    // LDS[chunk][row][p*16] = x[row][c*256 + (p*16 ^ (row&7)*16)]  (R16/17-verified)
    auto STAGE1 = [&](int c) {
        char* ld = ring + (c & 3) * 4096;
        #pragma unroll
        for (int u = 0; u < 4; ++u) {
            const int row = u * 4 + (l >> 4);
            const char* gs = gxt + (size_t)row * 8192 + c * 256
                           + (((l & 15) * 16) ^ ((row & 7) * 16));
            __builtin_amdgcn_global_load_lds((gu32*)gs, (lu32*)(ld + u * 1024), 16, 0, 0);
        }
    };
    // ph2 stage row r (8 KB linear): 8 DMA instrs.
    auto STAGE2 = [&](int r) {
        const char* gs = gxt + (size_t)r * 8192;
        char* ld = ring + (r & 1) * 8192;
        #pragma unroll
        for (int u = 0; u < 8; ++u)
            __builtin_amdgcn_global_load_lds((gu32*)(gs + u * 1024 + l * 16),
                                             (lu32*)(ld + u * 1024), 16, 0, 0);
    };

    f32x4 c0 = {0.f, 0.f, 0.f, 0.f};
    f32x4 c1 = {0.f, 0.f, 0.f, 0.f};

    STAGE1(0);
    STAGE1(1);

    // ---- phase 1: 32 chunk-iters, fixed VMEM rhythm [wait][tab x8][stage x4] ----
    const int row = l & 15;
    const int key = (row & 7) * 16;
    #pragma unroll 1
    for (int c = 0; c < 32; ++c) {
        // queue (newest->oldest) at top: stage(c+1)[4], tab(prev)[8], stage(c)[4], ...
        if (c == 0)      asm volatile("s_waitcnt vmcnt(4)" ::: "memory");
        else if (c < 31) asm volatile("s_waitcnt vmcnt(12)" ::: "memory");
        else             asm volatile("s_waitcnt vmcnt(8)" ::: "memory");
        __builtin_amdgcn_sched_barrier(0);

        const char* cb = ring + (c & 3) * 4096 + row * 256;
        #pragma unroll
        for (int ksl = 0; ksl < 2; ++ksl) {
            const int p = (l >> 4) * 2 + ksl * 8;
            const float4 xa  = *(const float4*)(cb + ((p * 16) ^ key));
            const float4 xb2 = *(const float4*)(cb + (((p + 1) * 16) ^ key));
            const int ksg = c * 2 + ksl;
            const short8* tp = (const short8*)(tab + (size_t)ksg * 2048);
            const short8 wh0 = tp[l];
            const short8 wl0 = tp[64 + l];
            const short8 wh1 = tp[128 + l];
            const short8 wl1 = tp[192 + l];
            short8 xhi, xlo;
            split8(xa, xb2, xhi, xlo);
            c0 = __builtin_amdgcn_mfma_f32_16x16x32_bf16(xhi, wh0, c0, 0, 0, 0);
            c1 = __builtin_amdgcn_mfma_f32_16x16x32_bf16(xhi, wh1, c1, 0, 0, 0);
            c0 = __builtin_amdgcn_mfma_f32_16x16x32_bf16(xhi, wl0, c0, 0, 0, 0);
            c1 = __builtin_amdgcn_mfma_f32_16x16x32_bf16(xhi, wl1, c1, 0, 0, 0);
            c0 = __builtin_amdgcn_mfma_f32_16x16x32_bf16(xlo, wh0, c0, 0, 0, 0);
            c1 = __builtin_amdgcn_mfma_f32_16x16x32_bf16(xlo, wh1, c1, 0, 0, 0);
        }
        __builtin_amdgcn_sched_barrier(0);
        if (c + 2 < 32) STAGE1(c + 2);
    }

    // ---- S -> LDS (m89 D-layout: row=(l>>4)*4+rr, col=l&15; c1 -> col+16) ----
    #pragma unroll
    for (int rr = 0; rr < 4; ++rr) {
        Sl[((l >> 4) * 4 + rr) * 36 + (l & 15)]      = c0[rr];
        Sl[((l >> 4) * 4 + rr) * 36 + 16 + (l & 15)] = c1[rr];
    }
    asm volatile("s_waitcnt lgkmcnt(0)" ::: "memory");   // S visible; ph1 ds ops retired
    __builtin_amdgcn_sched_barrier(0);

    STAGE2(0);
    STAGE2(1);

    // ---- phase 2: 16 row-iters, rhythm [wait][LDS dot + store][stage x8] ----
    #pragma unroll 1
    for (int r = 0; r < 16; ++r) {
        // queue at top: stage(r+1)[8], store(prev)[1], stage(r)[8], ...
        if (r == 0)      asm volatile("s_waitcnt vmcnt(8)" ::: "memory");
        else if (r < 15) asm volatile("s_waitcnt vmcnt(9)" ::: "memory");
        else             asm volatile("s_waitcnt vmcnt(1)" ::: "memory");
        __builtin_amdgcn_sched_barrier(0);

        const char* rb = ring + (r & 1) * 8192;
        const float* sp = Sl + r * 36;
        float s = 0.0f;
        #pragma unroll
        for (int q = 0; q < 8; ++q) {
            const int p = (q + l) & 7;                    // rotated slot: uniform bank use
            const float4 xv = *(const float4*)(rb + l * 128 + p * 16);
            const float4 sv = *(const float4*)(sp + p * 4);
            s += xv.x * sv.x + xv.y * sv.y + xv.z * sv.z + xv.w * sv.w;
        }
        const float e2 = __expf(2.0f * s);                // tanh = 1 - 2/(e^{2s}+1)
        out[(b0 + r) * 64 + l] = 1.0f - 2.0f / (e2 + 1.0f);
        __builtin_amdgcn_sched_barrier(0);
        if (r + 2 < 16) STAGE2(r + 2);
    }
}

extern "C" void kernel_launch(void* const* d_in, const int* in_sizes, int n_in,
                              void* d_out, int out_size, void* d_ws, size_t ws_size,
                              hipStream_t stream) {
    const float* x = (const float*)d_in[0];          // [65536,64,32] fp32
    const float* W = (const float*)d_in[1];          // [64,32,32] fp32
    float* out = (float*)d_out;                      // [65536,64] fp32
    unsigned short* tab = (unsigned short*)d_ws;     // 131072 ushorts = 256 KB

    const size_t smem_bytes = 4 * WLDS;              // 74752 B -> 2 blocks/CU
    hipFuncSetAttribute((const void*)ipf_kernel,
                        hipFuncAttributeMaxDynamicSharedMemorySize, (int)smem_bytes);

    wtab_kernel<<<64, 1024, 0, stream>>>(W, tab);
    ipf_kernel<<<1024, 256, smem_bytes, stream>>>(x, tab, out);
}